// Round 9
// baseline (318.485 us; speedup 1.0000x reference)
//
#include <hip/hip_runtime.h>
#include <cstdint>
#include <cstddef>

#define B_ 4
#define C_ 256
#define N_ 4096

typedef __attribute__((ext_vector_type(8))) short s8v;    // 8 bf16 MFMA A/B frag
typedef __attribute__((ext_vector_type(4))) float f4v;    // 16x16 C/D frag
typedef __attribute__((ext_vector_type(16))) float f16v;  // 32x32 C/D frag

#if defined(__has_builtin)
#if __has_builtin(__builtin_amdgcn_exp2f)
#define EXP2(x) __builtin_amdgcn_exp2f(x)
#endif
#endif
#ifndef EXP2
#define EXP2(x) exp2f(x)
#endif

__device__ __forceinline__ unsigned short f2bf(float f) {
  unsigned int u = __builtin_bit_cast(unsigned int, f);
  return (unsigned short)((u + 0x7FFFu + ((u >> 16) & 1u)) >> 16);  // RNE
}

// pack two positive floats to bf16x2 (truncation) in ONE v_perm_b32
__device__ __forceinline__ unsigned pk2bf_trunc(float lo, float hi) {
  return __builtin_amdgcn_perm(__builtin_bit_cast(unsigned, hi),
                               __builtin_bit_cast(unsigned, lo), 0x07060302u);
}

// Layouts:
//  xbB (16x16 B-frag, qkv input): ((b*256+(n>>4))*32+(c>>3))*128 + (n&15)*8 + (c&7)
//  aB  (16x16 B-frag, proj input): same formula
//  qBB/kBB (32-blocked): ((b*128+(n>>5))*16+(c>>4))*512 + (n&31)*16 + (c&15)
//  vBB (32-blocked):     ((b*8+(c>>5))*256+(j>>4))*512 + (c&31)*16 + (j&15)
//  32x32 MFMA frags: A[m=l&31][k=(l>>5)*8+j], B[k=(l>>5)*8+j][n=l&31],
//                    C/D: col=l&31, row=(r&3)+8*(r>>2)+4*(l>>5)

// ---------------- K1: BatchNorm statistics ----------------
__global__ __launch_bounds__(256) void bn_stats(const float* __restrict__ x,
                                                float* __restrict__ mean,
                                                float* __restrict__ rstd) {
  int c = blockIdx.x, t = threadIdx.x;
  float s = 0.f, s2 = 0.f;
  for (int b = 0; b < B_; ++b) {
    const float* p = x + ((size_t)b * C_ + c) * N_;
    for (int n = t; n < N_; n += 256) { float v = p[n]; s += v; s2 += v * v; }
  }
  __shared__ float rs[256], rs2[256];
  rs[t] = s; rs2[t] = s2; __syncthreads();
  for (int off = 128; off > 0; off >>= 1) {
    if (t < off) { rs[t] += rs[t + off]; rs2[t] += rs2[t + off]; }
    __syncthreads();
  }
  if (t == 0) {
    float m = rs[0] * (1.f / 16384.f);
    float v = rs2[0] * (1.f / 16384.f) - m * m;
    mean[c] = m; rstd[c] = rsqrtf(v + 1e-5f);
  }
}

// ---------------- K2: fold BN (and C^-0.5 * log2e into q path) into weights ----------------
__global__ __launch_bounds__(256) void prep(
    const float* __restrict__ wq, const float* __restrict__ bq,
    const float* __restrict__ wk, const float* __restrict__ bk,
    const float* __restrict__ wv, const float* __restrict__ bv,
    const float* __restrict__ wp,
    const float* __restrict__ gamma, const float* __restrict__ beta,
    const float* __restrict__ mean, const float* __restrict__ rstd,
    unsigned short* __restrict__ wqb, unsigned short* __restrict__ wkb,
    unsigned short* __restrict__ wvb, unsigned short* __restrict__ wpb,
    float* __restrict__ beq, float* __restrict__ bek, float* __restrict__ bev) {
  const float QSC = 0.0625f * 1.4426950408889634f;   // C^-0.5 * log2(e)
  int o = blockIdx.x, c = threadIdx.x;
  float a = gamma[c] * rstd[c];
  float d = beta[c] - mean[c] * a;
  float wqv = wq[o * C_ + c], wkv = wk[o * C_ + c], wvv = wv[o * C_ + c];
  wqb[o * C_ + c] = f2bf(wqv * a * QSC);
  wkb[o * C_ + c] = f2bf(wkv * a);
  wvb[o * C_ + c] = f2bf(wvv * a);
  wpb[o * C_ + c] = f2bf(wp[o * C_ + c]);
  __shared__ float r0[256], r1[256], r2[256];
  r0[c] = wqv * d; r1[c] = wkv * d; r2[c] = wvv * d; __syncthreads();
  for (int off = 128; off > 0; off >>= 1) {
    if (c < off) { r0[c] += r0[c + off]; r1[c] += r1[c + off]; r2[c] += r2[c + off]; }
    __syncthreads();
  }
  if (c == 0) {
    beq[o] = (bq[o] + r0[0]) * QSC;
    bek[o] = bk[o] + r1[0];
    bev[o] = bv[o] + r2[0];
  }
}

// ---------------- K2b: x -> blocked bf16 B-fragment layout ----------------
__global__ __launch_bounds__(256) void xt(const float* __restrict__ x,
                                          unsigned short* __restrict__ xbB) {
  int b = blockIdx.z, c0 = blockIdx.y * 64, n0 = blockIdx.x * 64;
  int tid = threadIdx.x;
  __shared__ unsigned short Ls[64][72];
  int cw = tid >> 6, nl = tid & 63;
#pragma unroll
  for (int rr = 0; rr < 16; ++rr) {
    int c = c0 + cw * 16 + rr;
    Ls[nl][cw * 16 + rr] = f2bf(x[((size_t)b * C_ + c) * N_ + n0 + nl]);
  }
  __syncthreads();
  int n_ = tid >> 2, cs = (tid & 3) * 16;
  s8v v0 = *(const s8v*)(&Ls[n_][cs]);
  s8v v1 = *(const s8v*)(&Ls[n_][cs + 8]);
  int n = n0 + n_;
  size_t base = (((size_t)b * 256 + (n >> 4)) * 32 + ((c0 + cs) >> 3)) * 128 + (n & 15) * 8;
  *(s8v*)(xbB + base) = v0;
  *(s8v*)(xbB + base + 128) = v1;
}

// ---------------- K3: fused QKV GEMM -> 32-blocked layouts ----------------
__global__ __launch_bounds__(256) void qkv(
    const unsigned short* __restrict__ xbB,
    const unsigned short* __restrict__ wqb, const unsigned short* __restrict__ wkb,
    const unsigned short* __restrict__ wvb,
    const float* __restrict__ beq, const float* __restrict__ bek,
    const float* __restrict__ bev,
    unsigned short* __restrict__ qBB, unsigned short* __restrict__ kBB,
    unsigned short* __restrict__ vBB) {
  int b = blockIdx.z, oblk = blockIdx.y, n0 = blockIdx.x * 64;
  int tid = threadIdx.x, w = tid >> 6, l = tid & 63, quad = l >> 4, lq = l & 15;
  int orow = oblk * 64 + w * 16 + lq;

  f4v aq[4], ak[4], av[4];
#pragma unroll
  for (int nt = 0; nt < 4; ++nt) {
    aq[nt] = (f4v){0.f, 0.f, 0.f, 0.f};
    ak[nt] = (f4v){0.f, 0.f, 0.f, 0.f};
    av[nt] = (f4v){0.f, 0.f, 0.f, 0.f};
  }

#pragma unroll
  for (int kk = 0; kk < 8; ++kk) {
    s8v afq = *(const s8v*)(wqb + (size_t)orow * C_ + kk * 32 + quad * 8);
    s8v afk = *(const s8v*)(wkb + (size_t)orow * C_ + kk * 32 + quad * 8);
    s8v afv = *(const s8v*)(wvb + (size_t)orow * C_ + kk * 32 + quad * 8);
#pragma unroll
    for (int nt = 0; nt < 4; ++nt) {
      s8v bf = *(const s8v*)(xbB + (((size_t)b * 256 + ((n0 + nt * 16) >> 4)) * 32 + kk * 4 + quad) * 128 + lq * 8);
      aq[nt] = __builtin_amdgcn_mfma_f32_16x16x32_bf16(afq, bf, aq[nt], 0, 0, 0);
      ak[nt] = __builtin_amdgcn_mfma_f32_16x16x32_bf16(afk, bf, ak[nt], 0, 0, 0);
      av[nt] = __builtin_amdgcn_mfma_f32_16x16x32_bf16(afv, bf, av[nt], 0, 0, 0);
    }
  }

  __shared__ unsigned short Ls[64][72];
  int obase = oblk * 64;

  // pass 1: q -> qBB ; pass 2: k -> kBB  ([n-blocked][c] layout)
  for (int pass = 0; pass < 2; ++pass) {
    const f4v* acc = (pass == 0) ? aq : ak;
    const float* BE = (pass == 0) ? beq : bek;
    unsigned short* dst = (pass == 0) ? qBB : kBB;
    int ob4 = obase + w * 16 + quad * 4;
    float b0 = BE[ob4], b1 = BE[ob4 + 1], b2 = BE[ob4 + 2], b3 = BE[ob4 + 3];
#pragma unroll
    for (int nt = 0; nt < 4; ++nt) {
      unsigned lo = (unsigned)f2bf(acc[nt][0] + b0) | ((unsigned)f2bf(acc[nt][1] + b1) << 16);
      unsigned hi2 = (unsigned)f2bf(acc[nt][2] + b2) | ((unsigned)f2bf(acc[nt][3] + b3) << 16);
      uint2 pr; pr.x = lo; pr.y = hi2;
      *(uint2*)(&Ls[nt * 16 + lq][w * 16 + quad * 4]) = pr;
    }
    __syncthreads();
    {
      int nl = tid >> 2, og = (tid & 3) * 16;
      s8v v0 = *(const s8v*)(&Ls[nl][og]);
      s8v v1 = *(const s8v*)(&Ls[nl][og + 8]);
      int n = n0 + nl, o = obase + og;
      size_t base = (((size_t)b * 128 + (n >> 5)) * 16 + (o >> 4)) * 512 + (size_t)(n & 31) * 16;
      *(s8v*)(dst + base) = v0;
      *(s8v*)(dst + base + 8) = v1;
    }
    __syncthreads();
  }

  // pass 3: v -> vBB ([c-blocked][j] layout)
#pragma unroll
  for (int nt = 0; nt < 4; ++nt)
#pragma unroll
    for (int r = 0; r < 4; ++r) {
      int o_ = obase + w * 16 + quad * 4 + r;
      Ls[w * 16 + quad * 4 + r][nt * 16 + lq] = f2bf(av[nt][r] + bev[o_]);
    }
  __syncthreads();
  {
    int ol = tid >> 2, ng = (tid & 3) * 16;
    s8v v0 = *(const s8v*)(&Ls[ol][ng]);
    s8v v1 = *(const s8v*)(&Ls[ol][ng + 8]);
    int o = obase + ol, n = n0 + ng;
    size_t base = (((size_t)b * 8 + (o >> 5)) * 256 + (n >> 4)) * 512 + (size_t)(o & 31) * 16;
    *(s8v*)(vBB + base) = v0;
    *(s8v*)(vBB + base + 8) = v1;
  }
}

// ---------------- K4: FMHA with 32x32x16 MFMA: 32 q-rows, 8 waves, 256-key chunks ----------------
// Wave w per chunk: S^T (its 32 keys x 32 rows, K=256) via 16 MFMAs; exp2; P to LDS
// (B-frag rows, 528B padded); ONE barrier; PV (its 32 channels x 32 rows over all
// 256 keys) via 16 MFMAs. k/v fragments prefetched in lo/hi halves across phases.
__global__ __launch_bounds__(512, 4) void attn(
    const unsigned short* __restrict__ qBB, const unsigned short* __restrict__ kBB,
    const unsigned short* __restrict__ vBB, unsigned short* __restrict__ aB) {
  int id = blockIdx.x;
  int xcd = id & 7, b = xcd >> 1;
  int i0 = ((id >> 3) * 2 + (xcd & 1)) * 32;   // 32 q-rows per block
  int tid = threadIdx.x, w = tid >> 6, l = tid & 63;
  int i = l & 31, hi = l >> 5;

  __shared__ unsigned short Qs[12288];     // [cb][i][24]  rows padded to 48B (24.6KB)
  __shared__ unsigned short Ps[2][8448];   // [i][264]     rows padded to 528B (2x16.9KB)
  __shared__ float Lw[8][32];

  // stage q tile: 16KB contiguous -> padded rows
  {
    const s8v* g = (const s8v*)(qBB + ((size_t)b * 128 + (i0 >> 5)) * 16 * 512);
#pragma unroll
    for (int it = 0; it < 2; ++it) {
      int gi = tid + it * 512;
      s8v v = g[gi];
      int cb = gi >> 6, rem = gi & 63;
      *(s8v*)(Qs + cb * 768 + (rem >> 1) * 24 + (rem & 1) * 8) = v;
    }
  }

  const unsigned short* kp = kBB + ((size_t)b * 128 + w) * 16 * 512 + i * 16 + hi * 8;
  const unsigned short* vp = vBB + ((size_t)b * 8 + w) * 256 * 512 + i * 16 + hi * 8;
  const unsigned short* Qp = Qs + i * 24 + hi * 8;
  unsigned short* Pwb = (unsigned short*)Ps + i * 264 + w * 32 + hi * 4;
  const unsigned short* Prb = (const unsigned short*)Ps + i * 264 + hi * 8;

  s8v kfl[8], kfh[8], vfl[8], vfh[8];
#pragma unroll
  for (int cb = 0; cb < 8; ++cb) kfl[cb] = *(const s8v*)(kp + cb * 512);

  f16v O;
#pragma unroll
  for (int r = 0; r < 16; ++r) O[r] = 0.f;
  float lsum = 0.f;

  __syncthreads();  // Qs visible

  for (int tt = 0; tt < 16; ++tt) {
#pragma unroll
    for (int half = 0; half < 2; ++half) {
      unsigned short* Pw = Pwb + half * 8448;
      const unsigned short* Pr = Prb + half * 8448;
      // kf_hi for THIS chunk (lands by S-half2)
#pragma unroll
      for (int cb = 0; cb < 8; ++cb) kfh[cb] = *(const s8v*)(kp + (cb + 8) * 512);
      f16v St;
#pragma unroll
      for (int r = 0; r < 16; ++r) St[r] = 0.f;
#pragma unroll
      for (int cb = 0; cb < 8; ++cb) {
        s8v qf = *(const s8v*)(Qp + cb * 768);
        St = __builtin_amdgcn_mfma_f32_32x32x16_bf16(kfl[cb], qf, St, 0, 0, 0);
      }
      // vf_lo for THIS chunk (lands by PV1, after the barrier)
#pragma unroll
      for (int jb = 0; jb < 8; ++jb) vfl[jb] = *(const s8v*)(vp + jb * 512);
#pragma unroll
      for (int cb = 0; cb < 8; ++cb) {
        s8v qf = *(const s8v*)(Qp + (cb + 8) * 768);
        St = __builtin_amdgcn_mfma_f32_32x32x16_bf16(kfh[cb], qf, St, 0, 0, 0);
      }
      // exp2 + pack + P write (4x 8B stores); j = w*32 + 8*g + 4*hi + (r&3)
#pragma unroll
      for (int g2 = 0; g2 < 4; ++g2) {
        float e0 = EXP2(St[g2 * 4 + 0]);
        float e1 = EXP2(St[g2 * 4 + 1]);
        float e2 = EXP2(St[g2 * 4 + 2]);
        float e3 = EXP2(St[g2 * 4 + 3]);
        lsum += (e0 + e1) + (e2 + e3);
        uint2 pr;
        pr.x = pk2bf_trunc(e0, e1);
        pr.y = pk2bf_trunc(e2, e3);
        *(uint2*)(Pw + g2 * 8) = pr;
      }
      __syncthreads();   // P visible; vf_lo already landed
      // NEXT chunk kf_lo + THIS chunk vf_hi (both land during PV1)
      kp += 65536;
#pragma unroll
      for (int cb = 0; cb < 8; ++cb) kfl[cb] = *(const s8v*)(kp + cb * 512);
#pragma unroll
      for (int jb = 0; jb < 8; ++jb) vfh[jb] = *(const s8v*)(vp + (jb + 8) * 512);
      // PV
#pragma unroll
      for (int jb = 0; jb < 8; ++jb) {
        s8v pf = *(const s8v*)(Pr + jb * 16);
        O = __builtin_amdgcn_mfma_f32_32x32x16_bf16(vfl[jb], pf, O, 0, 0, 0);
      }
#pragma unroll
      for (int jb = 0; jb < 8; ++jb) {
        s8v pf = *(const s8v*)(Pr + (jb + 8) * 16);
        O = __builtin_amdgcn_mfma_f32_32x32x16_bf16(vfh[jb], pf, O, 0, 0, 0);
      }
      vp += 8192;
    }
  }

  // lsum: each lane covers 16 of its wave's 32 keys (same row i); fold hi-halves
  lsum += __shfl_xor(lsum, 32);
  if (hi == 0) Lw[w][i] = lsum;
  __syncthreads();
  float s = 0.f;
#pragma unroll
  for (int ww = 0; ww < 8; ++ww) s += Lw[ww][i];
  float rl = 1.f / s;

  // store: c = w*32 + (r&3)+8*(r>>2)+4*hi, row = i0+i  -> aB (16x16 B-frag layout)
  int iout = i0 + i;
  size_t ob = (((size_t)b * 256 + (iout >> 4)) * 32 + w * 4) * 128 + (iout & 15) * 8 + hi * 4;
#pragma unroll
  for (int g2 = 0; g2 < 4; ++g2) {
    ushort4 pk;
    pk.x = f2bf(O[g2 * 4 + 0] * rl);
    pk.y = f2bf(O[g2 * 4 + 1] * rl);
    pk.z = f2bf(O[g2 * 4 + 2] * rl);
    pk.w = f2bf(O[g2 * 4 + 3] * rl);
    *(ushort4*)(aB + ob + g2 * 128) = pk;
  }
}

// ---------------- K5: projection + bias + residual ----------------
__global__ __launch_bounds__(256) void proj(
    const float* __restrict__ x, const unsigned short* __restrict__ wpb,
    const float* __restrict__ bp, const unsigned short* __restrict__ aB,
    float* __restrict__ out) {
  int b = blockIdx.z, oblk = blockIdx.y, n0 = blockIdx.x * 64;
  int tid = threadIdx.x, w = tid >> 6, l = tid & 63, quad = l >> 4, lq = l & 15;
  int orow_a = oblk * 64 + w * 16 + lq;

  f4v acc[4];
#pragma unroll
  for (int nt = 0; nt < 4; ++nt) acc[nt] = (f4v){0.f, 0.f, 0.f, 0.f};

#pragma unroll
  for (int kk = 0; kk < 8; ++kk) {
    s8v af = *(const s8v*)(wpb + (size_t)orow_a * C_ + kk * 32 + quad * 8);
#pragma unroll
    for (int nt = 0; nt < 4; ++nt) {
      s8v bf = *(const s8v*)(aB + (((size_t)b * 256 + ((n0 + nt * 16) >> 4)) * 32 + kk * 4 + quad) * 128 + lq * 8);
      acc[nt] = __builtin_amdgcn_mfma_f32_16x16x32_bf16(af, bf, acc[nt], 0, 0, 0);
    }
  }
#pragma unroll
  for (int nt = 0; nt < 4; ++nt)
#pragma unroll
    for (int r = 0; r < 4; ++r) {
      int o_ = oblk * 64 + w * 16 + quad * 4 + r;
      size_t idx = ((size_t)b * C_ + o_) * N_ + n0 + nt * 16 + lq;
      out[idx] = x[idx] + acc[nt][r] + bp[o_];
    }
}

extern "C" void kernel_launch(void* const* d_in, const int* in_sizes, int n_in,
                              void* d_out, int out_size, void* d_ws, size_t ws_size,
                              hipStream_t stream) {
  const float* x     = (const float*)d_in[0];
  const float* gamma = (const float*)d_in[1];
  const float* beta  = (const float*)d_in[2];
  const float* wq    = (const float*)d_in[3];
  const float* bq    = (const float*)d_in[4];
  const float* wk    = (const float*)d_in[5];
  const float* bk    = (const float*)d_in[6];
  const float* wv    = (const float*)d_in[7];
  const float* bv    = (const float*)d_in[8];
  const float* wp    = (const float*)d_in[9];
  const float* bp    = (const float*)d_in[10];
  float* out = (float*)d_out;

  char* ws = (char*)d_ws;
  float* mean = (float*)ws; ws += 1024;
  float* rstd = (float*)ws; ws += 1024;
  float* beq  = (float*)ws; ws += 1024;
  float* bek  = (float*)ws; ws += 1024;
  float* bev  = (float*)ws; ws += 1024;
  unsigned short* wqb = (unsigned short*)ws; ws += C_ * C_ * 2;
  unsigned short* wkb = (unsigned short*)ws; ws += C_ * C_ * 2;
  unsigned short* wvb = (unsigned short*)ws; ws += C_ * C_ * 2;
  unsigned short* wpb = (unsigned short*)ws; ws += C_ * C_ * 2;
  unsigned short* xbB = (unsigned short*)ws; ws += (size_t)B_ * N_ * C_ * 2;
  unsigned short* qBB = (unsigned short*)ws; ws += (size_t)B_ * N_ * C_ * 2;
  unsigned short* kBB = (unsigned short*)ws; ws += (size_t)B_ * N_ * C_ * 2;
  unsigned short* vBB = (unsigned short*)ws; ws += (size_t)B_ * N_ * C_ * 2;
  unsigned short* aB  = (unsigned short*)ws; ws += (size_t)B_ * N_ * C_ * 2;

  hipLaunchKernelGGL(bn_stats, dim3(C_), dim3(256), 0, stream, x, mean, rstd);
  hipLaunchKernelGGL(prep, dim3(C_), dim3(256), 0, stream,
                     wq, bq, wk, bk, wv, bv, wp, gamma, beta, mean, rstd,
                     wqb, wkb, wvb, wpb, beq, bek, bev);
  hipLaunchKernelGGL(xt, dim3(N_ / 64, 4, B_), dim3(256), 0, stream, x, xbB);
  hipLaunchKernelGGL(qkv, dim3(N_ / 64, 4, B_), dim3(256), 0, stream,
                     xbB, wqb, wkb, wvb, beq, bek, bev, qBB, kBB, vBB);
  hipLaunchKernelGGL(attn, dim3(512), dim3(512), 0, stream, qBB, kBB, vBB, aB);
  hipLaunchKernelGGL(proj, dim3(N_ / 64, 4, B_), dim3(256), 0, stream,
                     x, wpb, bp, aB, out);
}

// Round 10
// 304.186 us; speedup vs baseline: 1.0470x; 1.0470x over previous
//
#include <hip/hip_runtime.h>
#include <cstdint>
#include <cstddef>

#define B_ 4
#define C_ 256
#define N_ 4096

typedef __attribute__((ext_vector_type(8))) short s8v;   // 8 bf16 (4 VGPRs) MFMA A/B frag
typedef __attribute__((ext_vector_type(4))) float f4v;   // MFMA C/D frag

#if defined(__has_builtin)
#if __has_builtin(__builtin_amdgcn_exp2f)
#define EXP2(x) __builtin_amdgcn_exp2f(x)
#endif
#endif
#ifndef EXP2
#define EXP2(x) exp2f(x)
#endif

__device__ __forceinline__ unsigned short f2bf(float f) {
  unsigned int u = __builtin_bit_cast(unsigned int, f);
  return (unsigned short)((u + 0x7FFFu + ((u >> 16) & 1u)) >> 16);  // RNE
}

// pack two positive floats to bf16x2 (truncation) in ONE v_perm_b32
__device__ __forceinline__ unsigned pk2bf_trunc(float lo, float hi) {
  return __builtin_amdgcn_perm(__builtin_bit_cast(unsigned, hi),
                               __builtin_bit_cast(unsigned, lo), 0x07060302u);
}

// Blocked fragment layouts (all bf16):
//  xbB/qB/kB/aB: flat = ((b*256 + (n>>4))*32 + (c>>3))*128 + (n&15)*8 + (c&7)
//  vB:           flat = ((((b*64 + (j>>6))*16 + (c>>4))*8 + ((j>>3)&7))*128 + (c&15)*8 + (j&7)

// ---------------- K1: x -> blocked bf16 B-frag layout + BN statistics (fused) ----------------
// Per block (64n x 64c): converts the tile AND wave-reduces per-channel sum/sumsq,
// one atomicAdd pair per (block, channel). gsum/gsq zeroed by hipMemsetAsync.
__global__ __launch_bounds__(256) void xts(const float* __restrict__ x,
                                           unsigned short* __restrict__ xbB,
                                           float* __restrict__ gsum,
                                           float* __restrict__ gsq) {
  int b = blockIdx.z, c0 = blockIdx.y * 64, n0 = blockIdx.x * 64;
  int tid = threadIdx.x;
  __shared__ unsigned short Ls[64][72];
  int cw = tid >> 6, nl = tid & 63;   // one wave per cw: nl spans the full 64 lanes
#pragma unroll
  for (int rr = 0; rr < 16; ++rr) {
    int c = c0 + cw * 16 + rr;
    float v = x[((size_t)b * C_ + c) * N_ + n0 + nl];
    Ls[nl][cw * 16 + rr] = f2bf(v);
    float s1 = v, s2 = v * v;
#pragma unroll
    for (int off = 1; off < 64; off <<= 1) {
      s1 += __shfl_xor(s1, off);
      s2 += __shfl_xor(s2, off);
    }
    if (nl == 0) { atomicAdd(&gsum[c], s1); atomicAdd(&gsq[c], s2); }
  }
  __syncthreads();
  int n_ = tid >> 2, cs = (tid & 3) * 16;
  s8v v0 = *(const s8v*)(&Ls[n_][cs]);
  s8v v1 = *(const s8v*)(&Ls[n_][cs + 8]);
  int n = n0 + n_;
  size_t base = (((size_t)b * 256 + (n >> 4)) * 32 + ((c0 + cs) >> 3)) * 128 + (n & 15) * 8;
  *(s8v*)(xbB + base) = v0;
  *(s8v*)(xbB + base + 128) = v1;
}

// ---------------- K2: fold BN (and C^-0.5 * log2e into q path) into weights ----------------
__global__ __launch_bounds__(256) void prep(
    const float* __restrict__ wq, const float* __restrict__ bq,
    const float* __restrict__ wk, const float* __restrict__ bk,
    const float* __restrict__ wv, const float* __restrict__ bv,
    const float* __restrict__ wp,
    const float* __restrict__ gamma, const float* __restrict__ beta,
    const float* __restrict__ gsum, const float* __restrict__ gsq,
    unsigned short* __restrict__ wqb, unsigned short* __restrict__ wkb,
    unsigned short* __restrict__ wvb, unsigned short* __restrict__ wpb,
    float* __restrict__ beq, float* __restrict__ bek, float* __restrict__ bev) {
  const float QSC = 0.0625f * 1.4426950408889634f;   // C^-0.5 * log2(e)
  int o = blockIdx.x, c = threadIdx.x;
  float m = gsum[c] * (1.f / 16384.f);
  float var = gsq[c] * (1.f / 16384.f) - m * m;
  float rst = rsqrtf(var + 1e-5f);
  float a = gamma[c] * rst;
  float d = beta[c] - m * a;
  float wqv = wq[o * C_ + c], wkv = wk[o * C_ + c], wvv = wv[o * C_ + c];
  wqb[o * C_ + c] = f2bf(wqv * a * QSC);
  wkb[o * C_ + c] = f2bf(wkv * a);
  wvb[o * C_ + c] = f2bf(wvv * a);
  wpb[o * C_ + c] = f2bf(wp[o * C_ + c]);
  __shared__ float r0[256], r1[256], r2[256];
  r0[c] = wqv * d; r1[c] = wkv * d; r2[c] = wvv * d; __syncthreads();
  for (int off = 128; off > 0; off >>= 1) {
    if (c < off) { r0[c] += r0[c + off]; r1[c] += r1[c + off]; r2[c] += r2[c + off]; }
    __syncthreads();
  }
  if (c == 0) {
    beq[o] = (bq[o] + r0[0]) * QSC;
    bek[o] = bk[o] + r1[0];
    bev[o] = bv[o] + r2[0];
  }
}

// ---------------- K3: fused QKV GEMM (shared x-fragments), 3-barrier epilogue ----------------
__global__ __launch_bounds__(256) void qkv(
    const unsigned short* __restrict__ xbB,
    const unsigned short* __restrict__ wqb, const unsigned short* __restrict__ wkb,
    const unsigned short* __restrict__ wvb,
    const float* __restrict__ beq, const float* __restrict__ bek,
    const float* __restrict__ bev,
    unsigned short* __restrict__ qB, unsigned short* __restrict__ kB,
    unsigned short* __restrict__ vB) {
  int b = blockIdx.z, oblk = blockIdx.y, n0 = blockIdx.x * 64;
  int tid = threadIdx.x, w = tid >> 6, l = tid & 63, quad = l >> 4, lq = l & 15;
  int orow = oblk * 64 + w * 16 + lq;

  f4v aq[4], ak[4], av[4];
#pragma unroll
  for (int nt = 0; nt < 4; ++nt) {
    aq[nt] = (f4v){0.f, 0.f, 0.f, 0.f};
    ak[nt] = (f4v){0.f, 0.f, 0.f, 0.f};
    av[nt] = (f4v){0.f, 0.f, 0.f, 0.f};
  }

#pragma unroll
  for (int kk = 0; kk < 8; ++kk) {
    s8v afq = *(const s8v*)(wqb + (size_t)orow * C_ + kk * 32 + quad * 8);
    s8v afk = *(const s8v*)(wkb + (size_t)orow * C_ + kk * 32 + quad * 8);
    s8v afv = *(const s8v*)(wvb + (size_t)orow * C_ + kk * 32 + quad * 8);
#pragma unroll
    for (int nt = 0; nt < 4; ++nt) {
      s8v bf = *(const s8v*)(xbB + (((size_t)b * 256 + ((n0 + nt * 16) >> 4)) * 32 + kk * 4 + quad) * 128 + lq * 8);
      aq[nt] = __builtin_amdgcn_mfma_f32_16x16x32_bf16(afq, bf, aq[nt], 0, 0, 0);
      ak[nt] = __builtin_amdgcn_mfma_f32_16x16x32_bf16(afk, bf, ak[nt], 0, 0, 0);
      av[nt] = __builtin_amdgcn_mfma_f32_16x16x32_bf16(afv, bf, av[nt], 0, 0, 0);
    }
  }

  __shared__ unsigned short Ls0[64][72], Ls1[64][72];
  int obase = oblk * 64;

  // stage q into Ls0 AND k into Ls1, one barrier, store both ([n][c] blocked)
  {
    int ob4 = obase + w * 16 + quad * 4;
    float q0 = beq[ob4], q1 = beq[ob4 + 1], q2 = beq[ob4 + 2], q3 = beq[ob4 + 3];
    float k0 = bek[ob4], k1 = bek[ob4 + 1], k2 = bek[ob4 + 2], k3 = bek[ob4 + 3];
#pragma unroll
    for (int nt = 0; nt < 4; ++nt) {
      uint2 pq, pk;
      pq.x = (unsigned)f2bf(aq[nt][0] + q0) | ((unsigned)f2bf(aq[nt][1] + q1) << 16);
      pq.y = (unsigned)f2bf(aq[nt][2] + q2) | ((unsigned)f2bf(aq[nt][3] + q3) << 16);
      pk.x = (unsigned)f2bf(ak[nt][0] + k0) | ((unsigned)f2bf(ak[nt][1] + k1) << 16);
      pk.y = (unsigned)f2bf(ak[nt][2] + k2) | ((unsigned)f2bf(ak[nt][3] + k3) << 16);
      *(uint2*)(&Ls0[nt * 16 + lq][w * 16 + quad * 4]) = pq;
      *(uint2*)(&Ls1[nt * 16 + lq][w * 16 + quad * 4]) = pk;
    }
    __syncthreads();
    int n16rel = tid >> 6, g_rel = (tid >> 3) & 7, lq2 = (tid & 7) * 2;
    size_t base = (((size_t)b * 256 + (n0 >> 4) + n16rel) * 32 + (obase >> 3) + g_rel) * 128 + lq2 * 8;
    s8v q0v = *(const s8v*)(&Ls0[n16rel * 16 + lq2][g_rel * 8]);
    s8v q1v = *(const s8v*)(&Ls0[n16rel * 16 + lq2 + 1][g_rel * 8]);
    *(s8v*)(qB + base) = q0v;
    *(s8v*)(qB + base + 8) = q1v;
    s8v k0v = *(const s8v*)(&Ls1[n16rel * 16 + lq2][g_rel * 8]);
    s8v k1v = *(const s8v*)(&Ls1[n16rel * 16 + lq2 + 1][g_rel * 8]);
    *(s8v*)(kB + base) = k0v;
    *(s8v*)(kB + base + 8) = k1v;
    __syncthreads();
  }

  // v -> vB ([c][n] blocked)
#pragma unroll
  for (int nt = 0; nt < 4; ++nt)
#pragma unroll
    for (int r = 0; r < 4; ++r) {
      int o_ = obase + w * 16 + quad * 4 + r;
      Ls0[w * 16 + quad * 4 + r][nt * 16 + lq] = f2bf(av[nt][r] + bev[o_]);
    }
  __syncthreads();
  {
    int cb_rel = tid >> 6, hq = (tid >> 3) & 7, lq2 = (tid & 7) * 2;
    s8v v0 = *(const s8v*)(&Ls0[cb_rel * 16 + lq2][hq * 8]);
    s8v v1 = *(const s8v*)(&Ls0[cb_rel * 16 + lq2 + 1][hq * 8]);
    size_t base = ((((size_t)b * 64 + (n0 >> 6)) * 16 + oblk * 4 + cb_rel) * 8 + hq) * 128 + lq2 * 8;
    *(s8v*)(vB + base) = v0;
    *(s8v*)(vB + base + 8) = v1;
  }
}

// ---------------- K4: FMHA (R8 proven): 32 q-rows, 8 waves, pointer-incremented ----------------
__global__ __launch_bounds__(512, 4) void attn(
    const unsigned short* __restrict__ qB, const unsigned short* __restrict__ kB,
    const unsigned short* __restrict__ vB, unsigned short* __restrict__ aB) {
  int id = blockIdx.x;
  int xcd = id & 7, b = xcd >> 1;
  int i0 = ((id >> 3) * 2 + (xcd & 1)) * 32;   // 32 q-rows per block
  int tid = threadIdx.x, w = tid >> 6, l = tid & 63, quad = l >> 4, lq = l & 15;

  __shared__ unsigned short Qs[8192];      // 16 KB staged q-tile (blocked layout)
  __shared__ unsigned short Ps[2][4096];   // 2 x 8 KB P tiles
  __shared__ float Lw[8][2][16];

  // stage q-tile (contiguous 16 KB in qB)
  {
    const s8v* g = (const s8v*)(qB + ((size_t)b * 256 + (i0 >> 4)) * 32 * 128);
    s8v* sq = (s8v*)Qs;
    sq[tid] = g[tid];
    sq[tid + 512] = g[tid + 512];
  }

  // per-thread base pointers (element units); in-chunk offsets are constants
  const unsigned short* kp = kB + (((size_t)b * 256 + w) * 32 + quad) * 128 + lq * 8;
  const unsigned short* vp = vB + (((size_t)b * 64 * 16 + w * 2) * 8 + quad) * 128 + lq * 8;
  const unsigned short* Qp0 = Qs + quad * 128 + lq * 8;
  const unsigned short* Qp1 = Qp0 + 4096;
  int jg = w * 2 + (quad >> 1);
  unsigned short* Pw0 = Ps[0] + ((size_t)(jg * 32 + lq)) * 8 + (quad & 1) * 4;
  unsigned short* Pw1 = Ps[1] + ((size_t)(jg * 32 + lq)) * 8 + (quad & 1) * 4;
  const unsigned short* Pr0 = Ps[0] + quad * 256 + lq * 8;
  const unsigned short* Pr1 = Ps[1] + quad * 256 + lq * 8;

  // prologue: kf for chunk 0
  s8v kf[8];
#pragma unroll
  for (int kk = 0; kk < 8; ++kk) kf[kk] = *(const s8v*)(kp + kk * 512);

  __syncthreads();  // Qs visible

  f4v O[2][2];
  O[0][0] = (f4v){0.f, 0.f, 0.f, 0.f}; O[0][1] = (f4v){0.f, 0.f, 0.f, 0.f};
  O[1][0] = (f4v){0.f, 0.f, 0.f, 0.f}; O[1][1] = (f4v){0.f, 0.f, 0.f, 0.f};
  float lsum[2] = {0.f, 0.f};

  for (int tt = 0; tt < 16; ++tt) {
#pragma unroll
    for (int half = 0; half < 2; ++half) {
      unsigned short* Pw = half ? Pw1 : Pw0;
      const unsigned short* Pr = half ? Pr1 : Pr0;
      // ---- vf prefetch for THIS chunk (consumed after the barrier) ----
      s8v vf[8];
      vf[0] = *(const s8v*)(vp);
      vf[1] = *(const s8v*)(vp + 1024);
      vf[2] = *(const s8v*)(vp + 512);
      vf[3] = *(const s8v*)(vp + 1536);
      vf[4] = *(const s8v*)(vp + 16384);
      vf[5] = *(const s8v*)(vp + 17408);
      vf[6] = *(const s8v*)(vp + 16896);
      vf[7] = *(const s8v*)(vp + 17920);
      // ---- S phase: this wave's 16 keys, q from LDS ----
      f4v St[2];
      St[0] = (f4v){0.f, 0.f, 0.f, 0.f};
      St[1] = (f4v){0.f, 0.f, 0.f, 0.f};
#pragma unroll
      for (int kk = 0; kk < 8; ++kk) {
        s8v qf0 = *(const s8v*)(Qp0 + kk * 512);
        s8v qf1 = *(const s8v*)(Qp1 + kk * 512);
        St[0] = __builtin_amdgcn_mfma_f32_16x16x32_bf16(kf[kk], qf0, St[0], 0, 0, 0);
        St[1] = __builtin_amdgcn_mfma_f32_16x16x32_bf16(kf[kk], qf1, St[1], 0, 0, 0);
      }
      // exp2 + pack (1 perm per pair) + 8B LDS write per ig
#pragma unroll
      for (int ig = 0; ig < 2; ++ig) {
        float e0 = EXP2(St[ig][0]);
        float e1 = EXP2(St[ig][1]);
        float e2 = EXP2(St[ig][2]);
        float e3 = EXP2(St[ig][3]);
        lsum[ig] += (e0 + e1) + (e2 + e3);
        uint2 pr;
        pr.x = pk2bf_trunc(e0, e1);
        pr.y = pk2bf_trunc(e2, e3);
        *(uint2*)(Pw + ig * 128) = pr;
      }
      __syncthreads();   // P visible; vf already landed (issued before S)
      // ---- kf prefetch for NEXT chunk (lands during PV) ----
      kp += 32768;
#pragma unroll
      for (int kk = 0; kk < 8; ++kk) kf[kk] = *(const s8v*)(kp + kk * 512);
      // ---- PV phase: this wave's 32 channels, all 128 keys ----
#pragma unroll
      for (int ks = 0; ks < 4; ++ks) {
        s8v pf0 = *(const s8v*)(Pr + ks * 1024);
        s8v pf1 = *(const s8v*)(Pr + ks * 1024 + 128);
        O[0][0] = __builtin_amdgcn_mfma_f32_16x16x32_bf16(vf[ks * 2 + 0], pf0, O[0][0], 0, 0, 0);
        O[0][1] = __builtin_amdgcn_mfma_f32_16x16x32_bf16(vf[ks * 2 + 0], pf1, O[0][1], 0, 0, 0);
        O[1][0] = __builtin_amdgcn_mfma_f32_16x16x32_bf16(vf[ks * 2 + 1], pf0, O[1][0], 0, 0, 0);
        O[1][1] = __builtin_amdgcn_mfma_f32_16x16x32_bf16(vf[ks * 2 + 1], pf1, O[1][1], 0, 0, 0);
      }
      vp += 32768;
    }
  }

  // lsum: reduce over quads (keys on rows), publish, sum across the 8 waves
#pragma unroll
  for (int ig = 0; ig < 2; ++ig) {
    lsum[ig] += __shfl_xor(lsum[ig], 16);
    lsum[ig] += __shfl_xor(lsum[ig], 32);
  }
  if (quad == 0) { Lw[w][0][lq] = lsum[0]; Lw[w][1][lq] = lsum[1]; }
  __syncthreads();
  float rl[2];
#pragma unroll
  for (int ig = 0; ig < 2; ++ig) {
    float s = 0.f;
#pragma unroll
    for (int ww = 0; ww < 8; ++ww) s += Lw[ww][ig][lq];
    rl[ig] = 1.f / s;
  }

  // normalize + blocked store (each wave owns its 32 channels; no O combine)
#pragma unroll
  for (int ct = 0; ct < 2; ++ct)
#pragma unroll
    for (int ig = 0; ig < 2; ++ig) {
      ushort4 pk;
      pk.x = f2bf(O[ct][ig][0] * rl[ig]);
      pk.y = f2bf(O[ct][ig][1] * rl[ig]);
      pk.z = f2bf(O[ct][ig][2] * rl[ig]);
      pk.w = f2bf(O[ct][ig][3] * rl[ig]);
      int c0 = w * 32 + ct * 16 + quad * 4;
      size_t ob = (((size_t)b * 256 + (i0 >> 4) + ig) * 32 + (c0 >> 3)) * 128 + lq * 8 + (quad & 1) * 4;
      *(ushort4*)(aB + ob) = pk;
    }
}

// ---------------- K5: projection + bias + residual ----------------
__global__ __launch_bounds__(256) void proj(
    const float* __restrict__ x, const unsigned short* __restrict__ wpb,
    const float* __restrict__ bp, const unsigned short* __restrict__ aB,
    float* __restrict__ out) {
  int b = blockIdx.z, oblk = blockIdx.y, n0 = blockIdx.x * 64;
  int tid = threadIdx.x, w = tid >> 6, l = tid & 63, quad = l >> 4, lq = l & 15;
  int orow_a = oblk * 64 + w * 16 + lq;

  f4v acc[4];
#pragma unroll
  for (int nt = 0; nt < 4; ++nt) acc[nt] = (f4v){0.f, 0.f, 0.f, 0.f};

#pragma unroll
  for (int kk = 0; kk < 8; ++kk) {
    s8v af = *(const s8v*)(wpb + (size_t)orow_a * C_ + kk * 32 + quad * 8);
#pragma unroll
    for (int nt = 0; nt < 4; ++nt) {
      s8v bf = *(const s8v*)(aB + (((size_t)b * 256 + ((n0 + nt * 16) >> 4)) * 32 + kk * 4 + quad) * 128 + lq * 8);
      acc[nt] = __builtin_amdgcn_mfma_f32_16x16x32_bf16(af, bf, acc[nt], 0, 0, 0);
    }
  }
#pragma unroll
  for (int nt = 0; nt < 4; ++nt)
#pragma unroll
    for (int r = 0; r < 4; ++r) {
      int o_ = oblk * 64 + w * 16 + quad * 4 + r;
      size_t idx = ((size_t)b * C_ + o_) * N_ + n0 + nt * 16 + lq;
      out[idx] = x[idx] + acc[nt][r] + bp[o_];
    }
}

extern "C" void kernel_launch(void* const* d_in, const int* in_sizes, int n_in,
                              void* d_out, int out_size, void* d_ws, size_t ws_size,
                              hipStream_t stream) {
  const float* x     = (const float*)d_in[0];
  const float* gamma = (const float*)d_in[1];
  const float* beta  = (const float*)d_in[2];
  const float* wq    = (const float*)d_in[3];
  const float* bq    = (const float*)d_in[4];
  const float* wk    = (const float*)d_in[5];
  const float* bk    = (const float*)d_in[6];
  const float* wv    = (const float*)d_in[7];
  const float* bv    = (const float*)d_in[8];
  const float* wp    = (const float*)d_in[9];
  const float* bp    = (const float*)d_in[10];
  float* out = (float*)d_out;

  char* ws = (char*)d_ws;
  float* gsum = (float*)ws; ws += 1024;
  float* gsq  = (float*)ws; ws += 1024;
  float* beq  = (float*)ws; ws += 1024;
  float* bek  = (float*)ws; ws += 1024;
  float* bev  = (float*)ws; ws += 1024;
  unsigned short* wqb = (unsigned short*)ws; ws += C_ * C_ * 2;
  unsigned short* wkb = (unsigned short*)ws; ws += C_ * C_ * 2;
  unsigned short* wvb = (unsigned short*)ws; ws += C_ * C_ * 2;
  unsigned short* wpb = (unsigned short*)ws; ws += C_ * C_ * 2;
  unsigned short* xbB = (unsigned short*)ws; ws += (size_t)B_ * N_ * C_ * 2;
  unsigned short* qB  = (unsigned short*)ws; ws += (size_t)B_ * N_ * C_ * 2;
  unsigned short* kB  = (unsigned short*)ws; ws += (size_t)B_ * N_ * C_ * 2;
  unsigned short* vB  = (unsigned short*)ws; ws += (size_t)B_ * N_ * C_ * 2;
  unsigned short* aB  = (unsigned short*)ws; ws += (size_t)B_ * N_ * C_ * 2;

  hipMemsetAsync(gsum, 0, 2048, stream);   // zero gsum+gsq (adjacent)
  hipLaunchKernelGGL(xts, dim3(N_ / 64, 4, B_), dim3(256), 0, stream, x, xbB, gsum, gsq);
  hipLaunchKernelGGL(prep, dim3(C_), dim3(256), 0, stream,
                     wq, bq, wk, bk, wv, bv, wp, gamma, beta, gsum, gsq,
                     wqb, wkb, wvb, wpb, beq, bek, bev);
  hipLaunchKernelGGL(qkv, dim3(N_ / 64, 4, B_), dim3(256), 0, stream,
                     xbB, wqb, wkb, wvb, beq, bek, bev, qB, kB, vB);
  hipLaunchKernelGGL(attn, dim3(512), dim3(512), 0, stream, qB, kB, vB, aB);
  hipLaunchKernelGGL(proj, dim3(N_ / 64, 4, B_), dim3(256), 0, stream,
                     x, wpb, bp, aB, out);
}